// Round 5
// baseline (4252.125 us; speedup 1.0000x reference)
//
#include <hip/hip_runtime.h>
#include <math.h>

typedef float f32x4 __attribute__((ext_vector_type(4)));
typedef short s16x8 __attribute__((ext_vector_type(8)));
typedef unsigned short u16;

#define DI __device__ __forceinline__

// ---------- scalar helpers ----------
DI float bf2f(u16 h) { union { unsigned u; float f; } v; v.u = ((unsigned)h) << 16; return v.f; }
DI u16 f2bf(float f) {
  union { float f; unsigned u; } v; v.f = f;
  unsigned u = v.u;
  u += 0x7FFFu + ((u >> 16) & 1u);   // RNE
  return (u16)(u >> 16);
}
DI float tanh_fast(float x) {
  float e = __expf(2.f * x);
  return 1.f - 2.f / (e + 1.f);
}
DI float sigmoid_f(float x) { return 1.f / (1.f + __expf(-x)); }
DI float softplus_f(float x) { return fmaxf(x, 0.f) + log1pf(__expf(-fabsf(x))); }
DI f32x4 mfma16(s16x8 a, s16x8 b, f32x4 c) {
  return __builtin_amdgcn_mfma_f32_16x16x32_bf16(a, b, c, 0, 0, 0);
}
// Barrier with LDS drain only (global stores fire-and-forget; prefetch loads stay in flight)
DI void bar_lds() { asm volatile("s_waitcnt lgkmcnt(0)\n\ts_barrier" ::: "memory"); }
// fragment-major LDS address: A[row][k] lives at (k>>5)*512 + (((k>>3)&3)*16+row)*8 + (k&7)
DI int fa(int k, int row) { return ((k >> 5) << 9) + ((((k >> 3) & 3) * 16 + row) << 3) + (k & 7); }

union P16 { uint4 v[2]; u16 u[16]; };

// ---------- ws layout (u16 units) ----------
static constexpr size_t U_RNN = 0;          // Whh_b : KT=13 NT=28 (364 tiles)
static constexpr size_t U_C1  = 186368;     // Wc    : KT=4  NT=28 (112)
static constexpr size_t U_C2  = 243712;     // Wmu|Wsig : KT=13 NT=14 (182)
static constexpr size_t U_GA  = 336896;     // Wg1|Wh1  : KT=4  NT=28 (112)
static constexpr size_t U_GB  = 394240;     // Wg2|Wh2  : KT=7  NT=14 (98)
static constexpr size_t U_GC  = 444416;     // Wmg|Wsg  : KT=4  NT=14 (56)
static constexpr size_t U_E1  = 473088;     // We1 : KT=4 NT=7  (28)
static constexpr size_t U_E2  = 487424;     // We2 : KT=4 NT=7  (28)
static constexpr size_t U_E3  = 501760;     // We3 : KT=4 NT=6  (24)
static constexpr size_t U_IN  = 514048;     // Wih_b: KT=3 NT=25 (75)
static constexpr size_t U_SL  = 552448;     // slot buffer: [t][bid][thread(448)][16] u16
                                            // lifecycle per (t,bid) region:
                                            //   k_proj writes xb -> rnn reads+overwrites with h
                                            //   -> comb reads h, ph2 overwrites [0,1792) with z
                                            //   -> k_dec reads z.

// ---------- K0: pack all weight matrices into MFMA B-fragment order ----------
__global__ void k_pack(u16* __restrict__ ws,
    const float* __restrict__ Whh_b, const float* __restrict__ Wc,
    const float* __restrict__ Wmu, const float* __restrict__ Wsig,
    const float* __restrict__ Wg1, const float* __restrict__ Wh1,
    const float* __restrict__ Wg2, const float* __restrict__ Wh2,
    const float* __restrict__ Wmg, const float* __restrict__ Wsg,
    const float* __restrict__ We1, const float* __restrict__ We2,
    const float* __restrict__ We3, const float* __restrict__ Wih_b)
{
  int r = blockIdx.x, l = threadIdx.x;
  int region, local;
  if      (r < 364)  { region = 0; local = r; }
  else if (r < 476)  { region = 1; local = r - 364; }
  else if (r < 658)  { region = 2; local = r - 476; }
  else if (r < 770)  { region = 3; local = r - 658; }
  else if (r < 868)  { region = 4; local = r - 770; }
  else if (r < 924)  { region = 5; local = r - 868; }
  else if (r < 952)  { region = 6; local = r - 924; }
  else if (r < 980)  { region = 7; local = r - 952; }
  else if (r < 1004) { region = 8; local = r - 980; }
  else               { region = 9; local = r - 1004; }

  int NT; size_t base;
  switch (region) {
    case 0: NT = 28; base = U_RNN; break;
    case 1: NT = 28; base = U_C1;  break;
    case 2: NT = 14; base = U_C2;  break;
    case 3: NT = 28; base = U_GA;  break;
    case 4: NT = 14; base = U_GB;  break;
    case 5: NT = 14; base = U_GC;  break;
    case 6: NT = 7;  base = U_E1;  break;
    case 7: NT = 7;  base = U_E2;  break;
    case 8: NT = 6;  base = U_E3;  break;
    default:NT = 25; base = U_IN;  break;
  }
  int kt = local / NT, nt = local % NT;
  u16* out = ws + base + ((size_t)local * 64 + l) * 8;
  #pragma unroll
  for (int e = 0; e < 8; ++e) {
    int k = kt * 32 + (l >> 4) * 8 + e;
    int n = nt * 16 + (l & 15);
    float v = 0.f;
    switch (region) {
      case 0: if (n < 400 && k < 400) v = Whh_b[n * 400 + k]; break;
      case 1: if (n < 400 && k < 100) v = Wc[n * 100 + k]; break;
      case 2: if (n < 112) { if (n < 100 && k < 400) v = Wmu[n * 400 + k]; }
              else { int m = n - 112; if (m < 100 && k < 400) v = Wsig[m * 400 + k]; } break;
      case 3: if (n < 208) { if (n < 200 && k < 100) v = Wg1[n * 100 + k]; }
              else if (n < 416) { int m = n - 208; if (m < 200 && k < 100) v = Wh1[m * 100 + k]; } break;
      case 4: if (n < 112) { if (n < 100 && k < 200) v = Wg2[n * 200 + k]; }
              else { int m = n - 112; if (m < 100 && k < 200) v = Wh2[m * 200 + k]; } break;
      case 5: if (n < 112) { if (n < 100 && k < 100) v = Wmg[n * 100 + k]; }
              else { int m = n - 112; if (m < 100 && k < 100) v = Wsg[m * 100 + k]; } break;
      case 6: if (n < 100 && k < 100) v = We1[n * 100 + k]; break;
      case 7: if (n < 100 && k < 100) v = We2[n * 100 + k]; break;
      case 8: if (n < 88  && k < 100) v = We3[n * 100 + k]; break;
      default:if (n < 400 && k < 88)  v = Wih_b[n * 88 + k]; break;
    }
    out[e] = f2bf(v);
  }
}

// ---------- K1: xb -> slot buffer, in rnn-consumer layout ----------
__global__ __launch_bounds__(256) void k_proj(
    const float* __restrict__ x, const float* __restrict__ bih_b,
    const u16* __restrict__ pk_in, u16* __restrict__ slot)
{
  __shared__ __align__(16) u16 x_lds[16][104];
  const int tid = threadIdx.x;
  const int cblk = blockIdx.x;
  const int b = cblk >> 4, s0 = (cblk & 15) << 4;
  const float* xg = x + (size_t)cblk * 16 * 88;
  for (int idx = tid; idx < 16 * 104; idx += 256) {
    int r = idx / 104, k = idx % 104;
    x_lds[r][k] = (k < 88) ? f2bf(xg[r * 88 + k]) : (u16)0;
  }
  __syncthreads();
  const int w = tid >> 6, l = tid & 63, g = l >> 4, li = l & 15;
  const int bid2 = b >> 4, r2 = b & 15, g2 = r2 >> 2, q2 = r2 & 3;
  s16x8 a[3];
  #pragma unroll
  for (int kt = 0; kt < 3; ++kt)
    a[kt] = *(const s16x8*)&x_lds[li][kt * 32 + g * 8];
  for (int nt = w; nt < 25; nt += 4) {
    f32x4 acc = (f32x4){0.f, 0.f, 0.f, 0.f};
    #pragma unroll
    for (int kt = 0; kt < 3; ++kt) {
      s16x8 bfr = *(const s16x8*)(pk_in + ((size_t)(kt * 25 + nt) * 64 + l) * 8);
      acc = mfma16(a[kt], bfr, acc);
    }
    int i = nt * 16 + li;
    float bias = bih_b[i];
    // consumer slot coords: t = s, thread = (i>>6)*64 + g2*16 + (i&15), elem = ((i>>4)&3)*4 + q2
    int thr = ((i >> 6) << 6) + (g2 << 4) + (i & 15);
    int elem = (((i >> 4) & 3) << 2) + q2;
    #pragma unroll
    for (int q = 0; q < 4; ++q) {
      int s = s0 + g * 4 + q;
      slot[((size_t)(s * 8 + bid2) * 448 + thr) * 16 + elem] = f2bf(acc[q] + bias);
    }
  }
}

// ---------- K2: fused backward-RNN -> comb (blocks 0-7) + generative scan (blocks 8-15) ----------
__global__ __launch_bounds__(448) void k_scan(
    const u16* __restrict__ pk_rnn, const u16* __restrict__ pk_c1, const u16* __restrict__ pk_c2,
    const u16* __restrict__ pk_gA, const u16* __restrict__ pk_gB, const u16* __restrict__ pk_gC,
    u16* __restrict__ slot, const float* __restrict__ bhh_b,
    const float* __restrict__ bc, const float* __restrict__ bmu, const float* __restrict__ bsig,
    const float* __restrict__ noise_inf,
    const float* __restrict__ z0g, const float* __restrict__ bg1, const float* __restrict__ bh1,
    const float* __restrict__ bg2, const float* __restrict__ bh2,
    const float* __restrict__ bmg, const float* __restrict__ bsg,
    const float* __restrict__ noise_gen,
    float* __restrict__ mui, float* __restrict__ sgi,
    float* __restrict__ mug, float* __restrict__ sgg)
{
  __shared__ __align__(16) u16 sm[16384];        // 32 KiB
  const int tid = threadIdx.x;
  const int w = tid >> 6, l = tid & 63, g = l >> 4, li = l & 15;
  const int bid = blockIdx.x;

  // zero ALL of LDS once: pad regions must never hold garbage (round-3 bug class)
  {
    uint4 z4 = (uint4){0, 0, 0, 0};
    uint4* p = (uint4*)sm;
    for (int idx = tid; idx < 2048; idx += 448) p[idx] = z4;
  }
  __syncthreads();

  if (bid < 8) {
    const int b0 = bid * 16;
    { // ===== phase A: backward RNN, h = tanh(xb_t + h Whh^T + bhh), t = 255..0 =====
      u16* hbuf = sm;                 // frag-major double buffer: 2 * 13*512 (pre-zeroed)
      // ALL of Whh register-resident: 52 frags (~208 regs; AGPRs via unified file)
      s16x8 wf[4][13];
      #pragma unroll
      for (int nt_l = 0; nt_l < 4; ++nt_l) {
        int nt = w * 4 + nt_l;
        if (nt < 25) {
          #pragma unroll
          for (int kt = 0; kt < 13; ++kt)
            wf[nt_l][kt] = *(const s16x8*)(pk_rnn + ((size_t)(kt * 28 + nt) * 64 + l) * 8);
        }
      }
      float bias_r[4];
      #pragma unroll
      for (int nt_l = 0; nt_l < 4; ++nt_l) {
        int nt = w * 4 + nt_l;
        bias_r[nt_l] = (nt < 25) ? bhh_b[nt * 16 + li] : 0.f;
      }
      P16 pf;
      {
        size_t base = ((size_t)(255 * 8 + bid) * 448 + w * 64 + l) * 16;
        pf.v[0] = *(const uint4*)(slot + base);
        pf.v[1] = *(const uint4*)(slot + base + 8);
      }
      __syncthreads();
      int cur = 0;
      for (int t = 0; t < 256; ++t) {
        const int tt = 255 - t;
        f32x4 acc[4];
        #pragma unroll
        for (int i = 0; i < 4; ++i) acc[i] = (f32x4){0.f, 0.f, 0.f, 0.f};
        const u16* hb = hbuf + cur * 6656;
        #pragma unroll
        for (int kt = 0; kt < 13; ++kt) {
          s16x8 a = *(const s16x8*)(hb + kt * 512 + l * 8);
          #pragma unroll
          for (int nt_l = 0; nt_l < 4; ++nt_l)
            if (w * 4 + nt_l < 25) acc[nt_l] = mfma16(a, wf[nt_l][kt], acc[nt_l]);
        }
        P16 st; st.v[0] = (uint4){0,0,0,0}; st.v[1] = (uint4){0,0,0,0};
        #pragma unroll
        for (int nt_l = 0; nt_l < 4; ++nt_l) {
          if (w * 4 + nt_l < 25) {
            #pragma unroll
            for (int q = 0; q < 4; ++q) {
              float v = acc[nt_l][q] + bf2f(pf.u[nt_l * 4 + q]) + bias_r[nt_l];
              st.u[nt_l * 4 + q] = f2bf(tanh_fast(v));
            }
          }
        }
        { // global store first (fire-and-forget), then LDS scatter
          size_t base = ((size_t)(tt * 8 + bid) * 448 + w * 64 + l) * 16;
          *(uint4*)(slot + base) = st.v[0];
          *(uint4*)(slot + base + 8) = st.v[1];
        }
        u16* hn = hbuf + (cur ^ 1) * 6656;
        #pragma unroll
        for (int nt_l = 0; nt_l < 4; ++nt_l) {
          if (w * 4 + nt_l < 25) {
            int n = (w * 4 + nt_l) * 16 + li;
            #pragma unroll
            for (int q = 0; q < 4; ++q)
              hn[fa(n, 4 * g + q)] = st.u[nt_l * 4 + q];
          }
        }
        if (t < 255) {
          size_t nb = ((size_t)((tt - 1) * 8 + bid) * 448 + w * 64 + l) * 16;
          pf.v[0] = *(const uint4*)(slot + nb);
          pf.v[1] = *(const uint4*)(slot + nb + 8);
        }
        bar_lds();
        cur ^= 1;
      }
    }
    __syncthreads();   // full drain: h-slots visible to whole block; LDS reuse
    { // ===== phase B: comb scan =====
      u16* hbF = sm;          // frag-major h : 13*512
      u16* zbF = sm + 6656;   // frag-major z : 4*512
      for (int idx = tid; idx < 8704; idx += 448) sm[idx] = 0;
      s16x8 wC1[4][4], wMu[13], wSg[13];
      #pragma unroll
      for (int nt_l = 0; nt_l < 4; ++nt_l) {
        int nt = w * 4 + nt_l;
        if (nt < 25) {
          #pragma unroll
          for (int kt = 0; kt < 4; ++kt)
            wC1[nt_l][kt] = *(const s16x8*)(pk_c1 + ((size_t)(kt * 28 + nt) * 64 + l) * 8);
        }
      }
      #pragma unroll
      for (int kt = 0; kt < 13; ++kt) {
        wMu[kt] = *(const s16x8*)(pk_c2 + ((size_t)(kt * 14 + w) * 64 + l) * 8);
        wSg[kt] = *(const s16x8*)(pk_c2 + ((size_t)(kt * 14 + 7 + w) * 64 + l) * 8);
      }
      const int c = w * 16 + li;
      const bool cv = (c < 100);
      const float bmu_c = cv ? bmu[c] : 0.f;
      const float bsig_c = cv ? bsig[c] : 0.f;
      float bc_r[4];
      #pragma unroll
      for (int nt_l = 0; nt_l < 4; ++nt_l) {
        int nt = w * 4 + nt_l;
        bc_r[nt_l] = (nt < 25) ? bc[nt * 16 + li] : 0.f;
      }
      P16 pf;
      {
        size_t base = ((size_t)(0 * 8 + bid) * 448 + w * 64 + l) * 16;
        pf.v[0] = *(const uint4*)(slot + base);
        pf.v[1] = *(const uint4*)(slot + base + 8);
      }
      float pf_nz[4];
      #pragma unroll
      for (int q = 0; q < 4; ++q)
        pf_nz[q] = cv ? noise_inf[((size_t)0 * 128 + b0 + g * 4 + q) * 100 + c] : 0.f;
      __syncthreads();

      for (int t = 0; t < 256; ++t) {
        { // ph1: h = 0.5*(tanh(z Wc^T + bc) + hr_t)   [B-frags in regs]
          s16x8 az[4];
          #pragma unroll
          for (int kt = 0; kt < 4; ++kt)
            az[kt] = *(const s16x8*)(zbF + kt * 512 + l * 8);
          f32x4 a1[4];
          #pragma unroll
          for (int i = 0; i < 4; ++i) a1[i] = (f32x4){0.f, 0.f, 0.f, 0.f};
          #pragma unroll
          for (int kt = 0; kt < 4; ++kt) {
            #pragma unroll
            for (int nt_l = 0; nt_l < 4; ++nt_l)
              if (w * 4 + nt_l < 25) a1[nt_l] = mfma16(az[kt], wC1[nt_l][kt], a1[nt_l]);
          }
          #pragma unroll
          for (int nt_l = 0; nt_l < 4; ++nt_l) {
            if (w * 4 + nt_l < 25) {
              int n = (w * 4 + nt_l) * 16 + li;
              #pragma unroll
              for (int q = 0; q < 4; ++q) {
                float hv = 0.5f * (tanh_fast(a1[nt_l][q] + bc_r[nt_l]) + bf2f(pf.u[nt_l * 4 + q]));
                hbF[fa(n, 4 * g + q)] = f2bf(hv);
              }
            }
          }
          if (t < 255) {
            size_t nb = ((size_t)((t + 1) * 8 + bid) * 448 + w * 64 + l) * 16;
            pf.v[0] = *(const uint4*)(slot + nb);
            pf.v[1] = *(const uint4*)(slot + nb + 8);
          }
        }
        bar_lds();
        { // ph2: mu / var / z; z also dropped into slot region for k_dec
          f32x4 am = (f32x4){0.f,0.f,0.f,0.f}, as_ = am;
          #pragma unroll
          for (int kt = 0; kt < 13; ++kt) {
            s16x8 a = *(const s16x8*)(hbF + kt * 512 + l * 8);
            am = mfma16(a, wMu[kt], am);
            as_ = mfma16(a, wSg[kt], as_);
          }
          #pragma unroll
          for (int q = 0; q < 4; ++q) {
            int r = g * 4 + q;
            float mu = am[q] + bmu_c;
            float va = softplus_f(as_[q] + bsig_c);
            if (cv) {
              size_t o = ((size_t)(b0 + r) * 256 + t) * 100 + c;
              mui[o] = mu;
              sgi[o] = va;
              float z = mu + sqrtf(va) * pf_nz[q];
              zbF[fa(c, r)] = f2bf(z);
              slot[(size_t)(t * 8 + bid) * 7168 + r * 112 + c] = f2bf(z);
            }
          }
          if (t < 255) {
            #pragma unroll
            for (int q = 0; q < 4; ++q)
              if (cv) pf_nz[q] = noise_inf[((size_t)(t + 1) * 128 + b0 + g * 4 + q) * 100 + c];
          }
        }
        bar_lds();
      }
    }
  } else {
    // ===== generative scan (tr_step) =====
    const int b0 = (bid - 8) * 16;
    u16* zbF  = sm;          // 4*512
    u16* rhbF = sm + 2048;   // 4*512
    u16* t1F  = sm + 4096;   // 7*512
    u16* t2F  = sm + 7680;   // 7*512 (end 11264)
    for (int idx = tid; idx < 2048; idx += 448) {
      int r = idx >> 7, c = idx & 127;
      zbF[fa(c, r)] = (c < 100) ? f2bf(z0g[(b0 + r) * 100 + c]) : (u16)0;
    }
    s16x8 wA[4][4], wBg[7], wBh[7], wCm[4], wCs[4];
    #pragma unroll
    for (int nt_l = 0; nt_l < 4; ++nt_l) {
      int nt = w * 4 + nt_l;
      if (nt < 26) {
        #pragma unroll
        for (int kt = 0; kt < 4; ++kt)
          wA[nt_l][kt] = *(const s16x8*)(pk_gA + ((size_t)(kt * 28 + nt) * 64 + l) * 8);
      }
    }
    #pragma unroll
    for (int kt = 0; kt < 7; ++kt) {
      wBg[kt] = *(const s16x8*)(pk_gB + ((size_t)(kt * 14 + w) * 64 + l) * 8);
      wBh[kt] = *(const s16x8*)(pk_gB + ((size_t)(kt * 14 + 7 + w) * 64 + l) * 8);
    }
    #pragma unroll
    for (int kt = 0; kt < 4; ++kt) {
      wCm[kt] = *(const s16x8*)(pk_gC + ((size_t)(kt * 14 + w) * 64 + l) * 8);
      wCs[kt] = *(const s16x8*)(pk_gC + ((size_t)(kt * 14 + 7 + w) * 64 + l) * 8);
    }
    const int c = w * 16 + li;
    const bool cv = (c < 100);
    const float bg2_c = cv ? bg2[c] : 0.f;
    const float bh2_c = cv ? bh2[c] : 0.f;
    const float bmg_c = cv ? bmg[c] : 0.f;
    const float bsg_c = cv ? bsg[c] : 0.f;
    float b1r[4];
    #pragma unroll
    for (int nt_l = 0; nt_l < 4; ++nt_l) {
      int n = (w * 4 + nt_l) * 16 + li;
      bool is1 = n < 208;
      int j = is1 ? n : n - 208;
      b1r[nt_l] = (n < 416 && j < 200) ? (is1 ? bg1[j] : bh1[j]) : 0.f;
    }
    float pfn[4];
    #pragma unroll
    for (int q = 0; q < 4; ++q)
      pfn[q] = cv ? noise_gen[((size_t)0 * 128 + b0 + g * 4 + q) * 100 + c] : 0.f;
    __syncthreads();

    for (int t = 0; t < 256; ++t) {
      s16x8 az[4];
      #pragma unroll
      for (int kt = 0; kt < 4; ++kt)
        az[kt] = *(const s16x8*)(zbF + kt * 512 + l * 8);
      { // ph1: t1 = relu(z Wg1^T + bg1) ; t2 = relu(z Wh1^T + bh1)  [B in regs]
        f32x4 a1[4];
        #pragma unroll
        for (int i = 0; i < 4; ++i) a1[i] = (f32x4){0.f, 0.f, 0.f, 0.f};
        #pragma unroll
        for (int kt = 0; kt < 4; ++kt) {
          #pragma unroll
          for (int nt_l = 0; nt_l < 4; ++nt_l)
            if (w * 4 + nt_l < 26) a1[nt_l] = mfma16(az[kt], wA[nt_l][kt], a1[nt_l]);
        }
        #pragma unroll
        for (int nt_l = 0; nt_l < 4; ++nt_l) {
          int n = (w * 4 + nt_l) * 16 + li;
          if (n < 416) {
            bool is1 = n < 208;
            int j = is1 ? n : n - 208;
            u16* dst = is1 ? t1F : t2F;
            #pragma unroll
            for (int q = 0; q < 4; ++q)
              dst[fa(j, 4 * g + q)] = f2bf(fmaxf(a1[nt_l][q] + b1r[nt_l], 0.f));
          }
        }
      }
      bar_lds();
      float muq[4];
      { // ph2: g, h_prop, m0; mu in-register; rh -> frags
        f32x4 ag = (f32x4){0.f,0.f,0.f,0.f}, ah = ag, am = ag;
        #pragma unroll
        for (int kt = 0; kt < 7; ++kt) {
          s16x8 x1 = *(const s16x8*)(t1F + kt * 512 + l * 8);
          ag = mfma16(x1, wBg[kt], ag);
        }
        #pragma unroll
        for (int kt = 0; kt < 7; ++kt) {
          s16x8 x2 = *(const s16x8*)(t2F + kt * 512 + l * 8);
          ah = mfma16(x2, wBh[kt], ah);
        }
        #pragma unroll
        for (int kt = 0; kt < 4; ++kt) am = mfma16(az[kt], wCm[kt], am);
        #pragma unroll
        for (int q = 0; q < 4; ++q) {
          int r = g * 4 + q;
          float gv = sigmoid_f(ag[q] + bg2_c);
          float hp = ah[q] + bh2_c;
          float m0 = am[q] + bmg_c;
          muq[q] = hp * gv + m0 * (1.f - gv);
          rhbF[fa(c, r)] = f2bf(fmaxf(hp, 0.f));   // zero for c>=100 (zero-padded weights)
          if (cv) mug[((size_t)(b0 + r) * 256 + t) * 100 + c] = muq[q];
        }
      }
      bar_lds();
      { // ph3: sigma = softplus(relu(h_prop) Wsg^T + bsg) ; z update
        f32x4 as2 = (f32x4){0.f,0.f,0.f,0.f};
        #pragma unroll
        for (int kt = 0; kt < 4; ++kt) {
          s16x8 xr = *(const s16x8*)(rhbF + kt * 512 + l * 8);
          as2 = mfma16(xr, wCs[kt], as2);
        }
        #pragma unroll
        for (int q = 0; q < 4; ++q) {
          int r = g * 4 + q;
          float sg = softplus_f(as2[q] + bsg_c);
          if (cv) {
            sgg[((size_t)(b0 + r) * 256 + t) * 100 + c] = sg;
            zbF[fa(c, r)] = f2bf(muq[q] + sqrtf(sg) * pfn[q]);
          }
        }
        if (t < 255) {
          #pragma unroll
          for (int q = 0; q < 4; ++q)
            if (cv) pfn[q] = noise_gen[((size_t)(t + 1) * 128 + b0 + g * 4 + q) * 100 + c];
        }
      }
      bar_lds();
    }
  }
}

// ---------- K3: decoder, parallel over (B,S); z read from slot regions ----------
__global__ __launch_bounds__(448) void k_dec(
    const u16* __restrict__ slot,
    const u16* __restrict__ pk_e1, const u16* __restrict__ pk_e2, const u16* __restrict__ pk_e3,
    const float* __restrict__ be1, const float* __restrict__ be2, const float* __restrict__ be3,
    float* __restrict__ xh)
{
  __shared__ __align__(16) u16 sm[3 * 2176];
  u16* zb = sm; u16* e1b = sm + 2176; u16* e2b = sm + 4352;
  const int tid = threadIdx.x;
  const int w = tid >> 6, l = tid & 63, g = l >> 4, li = l & 15;
  const int cc = blockIdx.x;
  const int b = cc >> 4, s0 = (cc & 15) << 4;
  const int bid2 = b >> 4, r2 = b & 15;

  s16x8 w1[4], w2[4], w3[4];
  #pragma unroll
  for (int kt = 0; kt < 4; ++kt) {
    w1[kt] = *(const s16x8*)(pk_e1 + ((size_t)(kt * 7 + w) * 64 + l) * 8);
    w2[kt] = *(const s16x8*)(pk_e2 + ((size_t)(kt * 7 + w) * 64 + l) * 8);
    if (w < 6) w3[kt] = *(const s16x8*)(pk_e3 + ((size_t)(kt * 6 + w) * 64 + l) * 8);
  }
  {
    for (int idx = tid; idx < 224; idx += 448) {
      int r = idx / 14, cj = idx % 14;
      size_t src = ((size_t)((s0 + r) * 8 + bid2)) * 7168 + r2 * 112 + cj * 8;
      *(uint4*)(zb + r * 136 + cj * 8) = *(const uint4*)(slot + src);
    }
    for (int idx = tid; idx < 3 * 384; idx += 448) {   // zero the 24-col pads
      int bi = idx / 384, j = idx % 384;
      (sm + bi * 2176)[(j / 24) * 136 + 112 + (j % 24)] = 0;
    }
  }
  __syncthreads();
  const int c = w * 16 + li;
  { // e1 = relu(z We1^T + be1)
    f32x4 acc = (f32x4){0.f,0.f,0.f,0.f};
    #pragma unroll
    for (int kt = 0; kt < 4; ++kt) {
      s16x8 a = *(const s16x8*)(zb + li * 136 + kt * 32 + g * 8);
      acc = mfma16(a, w1[kt], acc);
    }
    float bias = (c < 100) ? be1[c] : 0.f;
    #pragma unroll
    for (int q = 0; q < 4; ++q)
      e1b[(g * 4 + q) * 136 + c] = f2bf(fmaxf(acc[q] + bias, 0.f));
  }
  bar_lds();
  { // e2 = relu(e1 We2^T + be2)
    f32x4 acc = (f32x4){0.f,0.f,0.f,0.f};
    #pragma unroll
    for (int kt = 0; kt < 4; ++kt) {
      s16x8 a = *(const s16x8*)(e1b + li * 136 + kt * 32 + g * 8);
      acc = mfma16(a, w2[kt], acc);
    }
    float bias = (c < 100) ? be2[c] : 0.f;
    #pragma unroll
    for (int q = 0; q < 4; ++q)
      e2b[(g * 4 + q) * 136 + c] = f2bf(fmaxf(acc[q] + bias, 0.f));
  }
  bar_lds();
  if (w < 6) { // x_hat = sigmoid(e2 We3^T + be3)
    f32x4 acc = (f32x4){0.f,0.f,0.f,0.f};
    #pragma unroll
    for (int kt = 0; kt < 4; ++kt) {
      s16x8 a = *(const s16x8*)(e2b + li * 136 + kt * 32 + g * 8);
      acc = mfma16(a, w3[kt], acc);
    }
    int n = w * 16 + li;
    if (n < 88) {
      float bias = be3[n];
      #pragma unroll
      for (int q = 0; q < 4; ++q)
        xh[((size_t)b * 256 + s0 + g * 4 + q) * 88 + n] = sigmoid_f(acc[q] + bias);
    }
  }
}

// ---------- host ----------
extern "C" void kernel_launch(void* const* d_in, const int* in_sizes, int n_in,
                              void* d_out, int out_size, void* d_ws, size_t ws_size,
                              hipStream_t stream) {
  const float* x      = (const float*)d_in[0];
  const float* Wih_b  = (const float*)d_in[5];
  const float* Whh_b  = (const float*)d_in[6];
  const float* bih_b  = (const float*)d_in[7];
  const float* bhh_b  = (const float*)d_in[8];
  const float* Wc     = (const float*)d_in[9];
  const float* bc     = (const float*)d_in[10];
  const float* Wmu    = (const float*)d_in[11];
  const float* bmu    = (const float*)d_in[12];
  const float* Wsig   = (const float*)d_in[13];
  const float* bsig   = (const float*)d_in[14];
  const float* We1    = (const float*)d_in[15];
  const float* be1    = (const float*)d_in[16];
  const float* We2    = (const float*)d_in[17];
  const float* be2    = (const float*)d_in[18];
  const float* We3    = (const float*)d_in[19];
  const float* be3    = (const float*)d_in[20];
  const float* Wg1    = (const float*)d_in[21];
  const float* bg1    = (const float*)d_in[22];
  const float* Wg2    = (const float*)d_in[23];
  const float* bg2    = (const float*)d_in[24];
  const float* Wh1    = (const float*)d_in[25];
  const float* bh1    = (const float*)d_in[26];
  const float* Wh2    = (const float*)d_in[27];
  const float* bh2    = (const float*)d_in[28];
  const float* Wmg    = (const float*)d_in[29];
  const float* bmg    = (const float*)d_in[30];
  const float* Wsg    = (const float*)d_in[31];
  const float* bsg    = (const float*)d_in[32];
  const float* noise_inf = (const float*)d_in[33];
  const float* z0_gen    = (const float*)d_in[34];
  const float* noise_gen = (const float*)d_in[35];

  u16* ws16 = (u16*)d_ws;
  float* out = (float*)d_out;
  float* xh  = out;                 // (B,S,88)
  float* mui = out + 2883584;       // (B,S,100)
  float* sgi = out + 6160384;
  float* mug = out + 9437184;
  float* sgg = out + 12713984;
  u16* slot = ws16 + U_SL;

  k_pack<<<1079, 64, 0, stream>>>(ws16, Whh_b, Wc, Wmu, Wsig, Wg1, Wh1, Wg2, Wh2,
                                  Wmg, Wsg, We1, We2, We3, Wih_b);
  k_proj<<<2048, 256, 0, stream>>>(x, bih_b, ws16 + U_IN, slot);
  k_scan<<<16, 448, 0, stream>>>(ws16 + U_RNN, ws16 + U_C1, ws16 + U_C2,
                                 ws16 + U_GA, ws16 + U_GB, ws16 + U_GC,
                                 slot, bhh_b,
                                 bc, bmu, bsig, noise_inf,
                                 z0_gen, bg1, bh1, bg2, bh2, bmg, bsg, noise_gen,
                                 mui, sgi, mug, sgg);
  k_dec<<<2048, 448, 0, stream>>>(slot, ws16 + U_E1, ws16 + U_E2, ws16 + U_E3,
                                  be1, be2, be3, xh);
}

// Round 6
// 2247.643 us; speedup vs baseline: 1.8918x; 1.8918x over previous
//
#include <hip/hip_runtime.h>
#include <math.h>

typedef float f32x4 __attribute__((ext_vector_type(4)));
typedef short s16x8 __attribute__((ext_vector_type(8)));
typedef unsigned short u16;
typedef unsigned int u32;

#define DI __device__ __forceinline__

// ---------- scalar helpers ----------
DI float bf2f(u16 h) { union { unsigned u; float f; } v; v.u = ((unsigned)h) << 16; return v.f; }
DI u16 f2bf(float f) {
  union { float f; unsigned u; } v; v.f = f;
  unsigned u = v.u;
  u += 0x7FFFu + ((u >> 16) & 1u);   // RNE
  return (u16)(u >> 16);
}
// HW packed f32x2 -> bf16x2 (RNE), 1 VALU op for 2 values
DI u32 cvt_pk(float lo, float hi) {
  u32 r;
  asm volatile("v_cvt_pk_bf16_f32 %0, %1, %2" : "=v"(r) : "v"(lo), "v"(hi));
  return r;
}
DI float tanh_fast(float x) {
  float e = __expf(2.f * x);
  return 1.f - 2.f / (e + 1.f);
}
DI float sigmoid_f(float x) { return 1.f / (1.f + __expf(-x)); }
DI float softplus_f(float x) { return fmaxf(x, 0.f) + log1pf(__expf(-fabsf(x))); }
DI f32x4 mfma16(s16x8 a, s16x8 b, f32x4 c) {
  return __builtin_amdgcn_mfma_f32_16x16x32_bf16(a, b, c, 0, 0, 0);
}
// Barrier with LDS drain only (global stores fire-and-forget; prefetch loads stay in flight)
DI void bar_lds() { asm volatile("s_waitcnt lgkmcnt(0)\n\ts_barrier" ::: "memory"); }
// fragment-major LDS address: A[row][k] lives at (k>>5)*512 + (((k>>3)&3)*16+row)*8 + (k&7)
DI int fa(int k, int row) { return ((k >> 5) << 9) + ((((k >> 3) & 3) * 16 + row) << 3) + (k & 7); }

union P16 { uint4 v[2]; u32 w32[8]; u16 u[16]; };

// ---------- ws layout (u16 units) ----------
static constexpr size_t U_RNN = 0;          // Whh_b : KT=13 NT=28 (364 tiles)
static constexpr size_t U_C1  = 186368;     // Wc    : KT=4  NT=28 (112)
static constexpr size_t U_C2  = 243712;     // Wmu|Wsig : KT=13 NT=14 (182)
static constexpr size_t U_GA  = 336896;     // Wg1|Wh1  : KT=4  NT=28 (112)
static constexpr size_t U_GB  = 394240;     // Wg2|Wh2  : KT=7  NT=14 (98)
static constexpr size_t U_GC  = 444416;     // Wmg|Wsg  : KT=4  NT=14 (56)
static constexpr size_t U_E1  = 473088;     // We1 : KT=4 NT=7  (28)
static constexpr size_t U_E2  = 487424;     // We2 : KT=4 NT=7  (28)
static constexpr size_t U_E3  = 501760;     // We3 : KT=4 NT=6  (24)
static constexpr size_t U_IN  = 514048;     // Wih_b: KT=3 NT=25 (75)
static constexpr size_t U_SL  = 552448;     // slot buffer: [t][bid][thread(448)][16] u16
                                            // lifecycle per (t,bid) region:
                                            //   k_proj writes xb(+both biases) -> rnn reads+overwrites with h
                                            //   -> comb reads h, ph2 overwrites [0,1792) with z
                                            //   -> k_dec reads z.

// ---------- K0: pack all weight matrices into MFMA B-fragment order ----------
__global__ void k_pack(u16* __restrict__ ws,
    const float* __restrict__ Whh_b, const float* __restrict__ Wc,
    const float* __restrict__ Wmu, const float* __restrict__ Wsig,
    const float* __restrict__ Wg1, const float* __restrict__ Wh1,
    const float* __restrict__ Wg2, const float* __restrict__ Wh2,
    const float* __restrict__ Wmg, const float* __restrict__ Wsg,
    const float* __restrict__ We1, const float* __restrict__ We2,
    const float* __restrict__ We3, const float* __restrict__ Wih_b)
{
  int r = blockIdx.x, l = threadIdx.x;
  int region, local;
  if      (r < 364)  { region = 0; local = r; }
  else if (r < 476)  { region = 1; local = r - 364; }
  else if (r < 658)  { region = 2; local = r - 476; }
  else if (r < 770)  { region = 3; local = r - 658; }
  else if (r < 868)  { region = 4; local = r - 770; }
  else if (r < 924)  { region = 5; local = r - 868; }
  else if (r < 952)  { region = 6; local = r - 924; }
  else if (r < 980)  { region = 7; local = r - 952; }
  else if (r < 1004) { region = 8; local = r - 980; }
  else               { region = 9; local = r - 1004; }

  int NT; size_t base;
  switch (region) {
    case 0: NT = 28; base = U_RNN; break;
    case 1: NT = 28; base = U_C1;  break;
    case 2: NT = 14; base = U_C2;  break;
    case 3: NT = 28; base = U_GA;  break;
    case 4: NT = 14; base = U_GB;  break;
    case 5: NT = 14; base = U_GC;  break;
    case 6: NT = 7;  base = U_E1;  break;
    case 7: NT = 7;  base = U_E2;  break;
    case 8: NT = 6;  base = U_E3;  break;
    default:NT = 25; base = U_IN;  break;
  }
  int kt = local / NT, nt = local % NT;
  u16* out = ws + base + ((size_t)local * 64 + l) * 8;
  #pragma unroll
  for (int e = 0; e < 8; ++e) {
    int k = kt * 32 + (l >> 4) * 8 + e;
    int n = nt * 16 + (l & 15);
    float v = 0.f;
    switch (region) {
      case 0: if (n < 400 && k < 400) v = Whh_b[n * 400 + k]; break;
      case 1: if (n < 400 && k < 100) v = Wc[n * 100 + k]; break;
      case 2: if (n < 112) { if (n < 100 && k < 400) v = Wmu[n * 400 + k]; }
              else { int m = n - 112; if (m < 100 && k < 400) v = Wsig[m * 400 + k]; } break;
      case 3: if (n < 208) { if (n < 200 && k < 100) v = Wg1[n * 100 + k]; }
              else if (n < 416) { int m = n - 208; if (m < 200 && k < 100) v = Wh1[m * 100 + k]; } break;
      case 4: if (n < 112) { if (n < 100 && k < 200) v = Wg2[n * 200 + k]; }
              else { int m = n - 112; if (m < 100 && k < 200) v = Wh2[m * 200 + k]; } break;
      case 5: if (n < 112) { if (n < 100 && k < 100) v = Wmg[n * 100 + k]; }
              else { int m = n - 112; if (m < 100 && k < 100) v = Wsg[m * 100 + k]; } break;
      case 6: if (n < 100 && k < 100) v = We1[n * 100 + k]; break;
      case 7: if (n < 100 && k < 100) v = We2[n * 100 + k]; break;
      case 8: if (n < 88  && k < 100) v = We3[n * 100 + k]; break;
      default:if (n < 400 && k < 88)  v = Wih_b[n * 88 + k]; break;
    }
    out[e] = f2bf(v);
  }
}

// ---------- K1: xb (+bih+bhh prefolded) -> slot buffer, in rnn-consumer layout ----------
__global__ __launch_bounds__(256) void k_proj(
    const float* __restrict__ x, const float* __restrict__ bih_b, const float* __restrict__ bhh_b,
    const u16* __restrict__ pk_in, u16* __restrict__ slot)
{
  __shared__ __align__(16) u16 x_lds[16][104];
  const int tid = threadIdx.x;
  const int cblk = blockIdx.x;
  const int b = cblk >> 4, s0 = (cblk & 15) << 4;
  const float* xg = x + (size_t)cblk * 16 * 88;
  for (int idx = tid; idx < 16 * 104; idx += 256) {
    int r = idx / 104, k = idx % 104;
    x_lds[r][k] = (k < 88) ? f2bf(xg[r * 88 + k]) : (u16)0;
  }
  __syncthreads();
  const int w = tid >> 6, l = tid & 63, g = l >> 4, li = l & 15;
  const int bid2 = b >> 4, r2 = b & 15, g2 = r2 >> 2, q2 = r2 & 3;
  s16x8 a[3];
  #pragma unroll
  for (int kt = 0; kt < 3; ++kt)
    a[kt] = *(const s16x8*)&x_lds[li][kt * 32 + g * 8];
  for (int nt = w; nt < 25; nt += 4) {
    f32x4 acc = (f32x4){0.f, 0.f, 0.f, 0.f};
    #pragma unroll
    for (int kt = 0; kt < 3; ++kt) {
      s16x8 bfr = *(const s16x8*)(pk_in + ((size_t)(kt * 25 + nt) * 64 + l) * 8);
      acc = mfma16(a[kt], bfr, acc);
    }
    int i = nt * 16 + li;
    float bias = bih_b[i] + bhh_b[i];     // prefold BOTH biases
    // consumer slot coords: t = s, thread = (i>>6)*64 + g2*16 + (i&15), elem = ((i>>4)&3)*4 + q2
    int thr = ((i >> 6) << 6) + (g2 << 4) + (i & 15);
    int elem = (((i >> 4) & 3) << 2) + q2;
    #pragma unroll
    for (int q = 0; q < 4; ++q) {
      int s = s0 + g * 4 + q;
      slot[((size_t)(s * 8 + bid2) * 448 + thr) * 16 + elem] = f2bf(acc[q] + bias);
    }
  }
}

// ---------- K2: fused backward-RNN -> comb (blocks 0-7) + generative scan (blocks 8-15) ----------
__global__ __launch_bounds__(448) void k_scan(
    const u16* __restrict__ pk_rnn, const u16* __restrict__ pk_c1, const u16* __restrict__ pk_c2,
    const u16* __restrict__ pk_gA, const u16* __restrict__ pk_gB, const u16* __restrict__ pk_gC,
    u16* __restrict__ slot,
    const float* __restrict__ bc, const float* __restrict__ bmu, const float* __restrict__ bsig,
    const float* __restrict__ noise_inf,
    const float* __restrict__ z0g, const float* __restrict__ bg1, const float* __restrict__ bh1,
    const float* __restrict__ bg2, const float* __restrict__ bh2,
    const float* __restrict__ bmg, const float* __restrict__ bsg,
    const float* __restrict__ noise_gen,
    float* __restrict__ mui, float* __restrict__ sgi,
    float* __restrict__ mug, float* __restrict__ sgg)
{
  __shared__ __align__(16) u16 sm[56320];        // 112,640 B
  const int tid = threadIdx.x;
  const int w = tid >> 6, l = tid & 63, g = l >> 4, li = l & 15;
  const int bid = blockIdx.x;

  // defensive: zero all LDS once (round-3 bug class)
  {
    uint4 z4 = (uint4){0, 0, 0, 0};
    uint4* p = (uint4*)sm;
    for (int idx = tid; idx < 7040; idx += 448) p[idx] = z4;
  }
  __syncthreads();

  if (bid < 8) {
    const int b0 = bid * 16;
    { // ===== phase A: backward RNN, h = tanh(xb_t + h Whh^T), biases prefolded, t = 255..0 =====
      u16* slab = sm;                 // Whh kt 10..12 : 3*28 = 84 tiles = 43008 u16
      u16* hbuf = sm + 43008;         // frag-major double buffer: 2 * 13*512 (pre-zeroed)
      {
        const uint4* src = (const uint4*)(pk_rnn + (size_t)10 * 28 * 512);
        uint4* dst = (uint4*)slab;
        for (int idx = tid; idx < 5376; idx += 448) dst[idx] = src[idx];
      }
      s16x8 wf[4][10];                // kt 0..9 in regs, ALL 28 nt loaded (proven round-4 budget)
      #pragma unroll
      for (int nt_l = 0; nt_l < 4; ++nt_l) {
        int nt = w * 4 + nt_l;
        #pragma unroll
        for (int kt = 0; kt < 10; ++kt)
          wf[nt_l][kt] = *(const s16x8*)(pk_rnn + ((size_t)(kt * 28 + nt) * 64 + l) * 8);
      }
      P16 pf;
      {
        size_t base = ((size_t)(255 * 8 + bid) * 448 + w * 64 + l) * 16;
        pf.v[0] = *(const uint4*)(slot + base);
        pf.v[1] = *(const uint4*)(slot + base + 8);
      }
      __syncthreads();

      auto step = [&](const u16* hb, u16* hn, int t) {
        const int tt = 255 - t;
        f32x4 acc[4];
        #pragma unroll
        for (int i = 0; i < 4; ++i) acc[i] = (f32x4){0.f, 0.f, 0.f, 0.f};
        if (w < 6) {
          #pragma unroll
          for (int kt = 0; kt < 13; ++kt) {
            s16x8 a = *(const s16x8*)(hb + kt * 512 + l * 8);
            if (kt < 10) {
              #pragma unroll
              for (int nt_l = 0; nt_l < 4; ++nt_l) acc[nt_l] = mfma16(a, wf[nt_l][kt], acc[nt_l]);
            } else {
              #pragma unroll
              for (int nt_l = 0; nt_l < 4; ++nt_l) {
                s16x8 bfr = *(const s16x8*)(slab + ((size_t)((kt - 10) * 28 + w * 4 + nt_l) * 512) + l * 8);
                acc[nt_l] = mfma16(a, bfr, acc[nt_l]);
              }
            }
          }
        } else {        // wave 6: only nt=24 valid (25 tiles total)
          #pragma unroll
          for (int kt = 0; kt < 13; ++kt) {
            s16x8 a = *(const s16x8*)(hb + kt * 512 + l * 8);
            if (kt < 10) acc[0] = mfma16(a, wf[0][kt], acc[0]);
            else {
              s16x8 bfr = *(const s16x8*)(slab + ((size_t)((kt - 10) * 28 + w * 4) * 512) + l * 8);
              acc[0] = mfma16(a, bfr, acc[0]);
            }
          }
        }
        const int nvmax = (w < 6) ? 4 : 1;
        P16 st; st.v[0] = (uint4){0,0,0,0}; st.v[1] = (uint4){0,0,0,0};
        for (int nt_l = 0; nt_l < nvmax; ++nt_l) {
          float t0 = tanh_fast(acc[nt_l][0] + bf2f(pf.u[nt_l * 4 + 0]));
          float t1 = tanh_fast(acc[nt_l][1] + bf2f(pf.u[nt_l * 4 + 1]));
          float t2 = tanh_fast(acc[nt_l][2] + bf2f(pf.u[nt_l * 4 + 2]));
          float t3 = tanh_fast(acc[nt_l][3] + bf2f(pf.u[nt_l * 4 + 3]));
          st.w32[nt_l * 2]     = cvt_pk(t0, t1);
          st.w32[nt_l * 2 + 1] = cvt_pk(t2, t3);
        }
        { // global store first (fire-and-forget), then LDS scatter
          size_t base = ((size_t)(tt * 8 + bid) * 448 + w * 64 + l) * 16;
          *(uint4*)(slot + base) = st.v[0];
          *(uint4*)(slot + base + 8) = st.v[1];
        }
        for (int nt_l = 0; nt_l < nvmax; ++nt_l) {
          int n = (w * 4 + nt_l) * 16 + li;
          #pragma unroll
          for (int q = 0; q < 4; ++q)
            hn[fa(n, 4 * g + q)] = st.u[nt_l * 4 + q];
        }
        if (t < 255) {
          size_t nb = ((size_t)((tt - 1) * 8 + bid) * 448 + w * 64 + l) * 16;
          pf.v[0] = *(const uint4*)(slot + nb);
          pf.v[1] = *(const uint4*)(slot + nb + 8);
        }
        bar_lds();
      };
      for (int t = 0; t < 256; t += 2) {      // unroll-2: compile-time buffer bases
        step(hbuf, hbuf + 6656, t);
        step(hbuf + 6656, hbuf, t + 1);
      }
    }
    __syncthreads();   // full drain: h-slots visible to whole block; LDS reuse
    { // ===== phase B: comb scan =====
      u16* hbF = sm;          // frag-major h : 13*512
      u16* zbF = sm + 6656;   // frag-major z : 4*512
      for (int idx = tid; idx < 8704; idx += 448) sm[idx] = 0;
      s16x8 wC1[4][4], wMu[13], wSg[13];
      #pragma unroll
      for (int nt_l = 0; nt_l < 4; ++nt_l) {
        int nt = w * 4 + nt_l;
        #pragma unroll
        for (int kt = 0; kt < 4; ++kt)
          wC1[nt_l][kt] = *(const s16x8*)(pk_c1 + ((size_t)(kt * 28 + nt) * 64 + l) * 8);
      }
      #pragma unroll
      for (int kt = 0; kt < 13; ++kt) {
        wMu[kt] = *(const s16x8*)(pk_c2 + ((size_t)(kt * 14 + w) * 64 + l) * 8);
        wSg[kt] = *(const s16x8*)(pk_c2 + ((size_t)(kt * 14 + 7 + w) * 64 + l) * 8);
      }
      const int c = w * 16 + li;
      const bool cv = (c < 100);
      const float bmu_c = cv ? bmu[c] : 0.f;
      const float bsig_c = cv ? bsig[c] : 0.f;
      float bc_r[4];
      #pragma unroll
      for (int nt_l = 0; nt_l < 4; ++nt_l) {
        int nt = w * 4 + nt_l;
        bc_r[nt_l] = (nt < 25) ? bc[nt * 16 + li] : 0.f;
      }
      P16 pf;
      {
        size_t base = ((size_t)(0 * 8 + bid) * 448 + w * 64 + l) * 16;
        pf.v[0] = *(const uint4*)(slot + base);
        pf.v[1] = *(const uint4*)(slot + base + 8);
      }
      float pf_nz[4];
      #pragma unroll
      for (int q = 0; q < 4; ++q)
        pf_nz[q] = cv ? noise_inf[((size_t)0 * 128 + b0 + g * 4 + q) * 100 + c] : 0.f;
      __syncthreads();

      const int nvmax = (w < 6) ? 4 : 1;
      for (int t = 0; t < 256; ++t) {
        { // ph1: h = 0.5*(tanh(z Wc^T + bc) + hr_t)
          s16x8 az[4];
          #pragma unroll
          for (int kt = 0; kt < 4; ++kt)
            az[kt] = *(const s16x8*)(zbF + kt * 512 + l * 8);
          f32x4 a1[4];
          #pragma unroll
          for (int i = 0; i < 4; ++i) a1[i] = (f32x4){0.f, 0.f, 0.f, 0.f};
          if (w < 6) {
            #pragma unroll
            for (int kt = 0; kt < 4; ++kt) {
              #pragma unroll
              for (int nt_l = 0; nt_l < 4; ++nt_l) a1[nt_l] = mfma16(az[kt], wC1[nt_l][kt], a1[nt_l]);
            }
          } else {
            #pragma unroll
            for (int kt = 0; kt < 4; ++kt) a1[0] = mfma16(az[kt], wC1[0][kt], a1[0]);
          }
          for (int nt_l = 0; nt_l < nvmax; ++nt_l) {
            int n = (w * 4 + nt_l) * 16 + li;
            float h0 = 0.5f * (tanh_fast(a1[nt_l][0] + bc_r[nt_l]) + bf2f(pf.u[nt_l * 4 + 0]));
            float h1 = 0.5f * (tanh_fast(a1[nt_l][1] + bc_r[nt_l]) + bf2f(pf.u[nt_l * 4 + 1]));
            float h2 = 0.5f * (tanh_fast(a1[nt_l][2] + bc_r[nt_l]) + bf2f(pf.u[nt_l * 4 + 2]));
            float h3 = 0.5f * (tanh_fast(a1[nt_l][3] + bc_r[nt_l]) + bf2f(pf.u[nt_l * 4 + 3]));
            u32 p01 = cvt_pk(h0, h1), p23 = cvt_pk(h2, h3);
            hbF[fa(n, 4 * g + 0)] = (u16)p01;
            hbF[fa(n, 4 * g + 1)] = (u16)(p01 >> 16);
            hbF[fa(n, 4 * g + 2)] = (u16)p23;
            hbF[fa(n, 4 * g + 3)] = (u16)(p23 >> 16);
          }
          if (t < 255) {
            size_t nb = ((size_t)((t + 1) * 8 + bid) * 448 + w * 64 + l) * 16;
            pf.v[0] = *(const uint4*)(slot + nb);
            pf.v[1] = *(const uint4*)(slot + nb + 8);
          }
        }
        bar_lds();
        { // ph2: mu / var / z; z also dropped into slot region for k_dec
          f32x4 am = (f32x4){0.f,0.f,0.f,0.f}, as_ = am;
          #pragma unroll
          for (int kt = 0; kt < 13; ++kt) {
            s16x8 a = *(const s16x8*)(hbF + kt * 512 + l * 8);
            am = mfma16(a, wMu[kt], am);
            as_ = mfma16(a, wSg[kt], as_);
          }
          if (cv) {
            float mu[4], va[4], z[4];
            #pragma unroll
            for (int q = 0; q < 4; ++q) {
              mu[q] = am[q] + bmu_c;
              va[q] = softplus_f(as_[q] + bsig_c);
              z[q] = mu[q] + sqrtf(va[q]) * pf_nz[q];
            }
            u32 p01 = cvt_pk(z[0], z[1]), p23 = cvt_pk(z[2], z[3]);
            u16 zb16[4] = { (u16)p01, (u16)(p01 >> 16), (u16)p23, (u16)(p23 >> 16) };
            #pragma unroll
            for (int q = 0; q < 4; ++q) {
              int r = g * 4 + q;
              size_t o = ((size_t)(b0 + r) * 256 + t) * 100 + c;
              mui[o] = mu[q];
              sgi[o] = va[q];
              zbF[fa(c, r)] = zb16[q];
              slot[(size_t)(t * 8 + bid) * 7168 + r * 112 + c] = zb16[q];
            }
          }
          if (t < 255) {
            #pragma unroll
            for (int q = 0; q < 4; ++q)
              if (cv) pf_nz[q] = noise_inf[((size_t)(t + 1) * 128 + b0 + g * 4 + q) * 100 + c];
          }
        }
        bar_lds();
      }
    }
  } else {
    // ===== generative scan (tr_step) =====
    const int b0 = (bid - 8) * 16;
    u16* zbF  = sm;          // 4*512
    u16* rhbF = sm + 2048;   // 4*512
    u16* t1F  = sm + 4096;   // 7*512
    u16* t2F  = sm + 7680;   // 7*512 (end 11264)
    for (int idx = tid; idx < 2048; idx += 448) {
      int r = idx >> 7, c = idx & 127;
      zbF[fa(c, r)] = (c < 100) ? f2bf(z0g[(b0 + r) * 100 + c]) : (u16)0;
    }
    s16x8 wA[4][4], wBg[7], wBh[7], wCm[4], wCs[4];
    #pragma unroll
    for (int nt_l = 0; nt_l < 4; ++nt_l) {
      int nt = w * 4 + nt_l;
      #pragma unroll
      for (int kt = 0; kt < 4; ++kt)
        wA[nt_l][kt] = *(const s16x8*)(pk_gA + ((size_t)(kt * 28 + nt) * 64 + l) * 8);
    }
    #pragma unroll
    for (int kt = 0; kt < 7; ++kt) {
      wBg[kt] = *(const s16x8*)(pk_gB + ((size_t)(kt * 14 + w) * 64 + l) * 8);
      wBh[kt] = *(const s16x8*)(pk_gB + ((size_t)(kt * 14 + 7 + w) * 64 + l) * 8);
    }
    #pragma unroll
    for (int kt = 0; kt < 4; ++kt) {
      wCm[kt] = *(const s16x8*)(pk_gC + ((size_t)(kt * 14 + w) * 64 + l) * 8);
      wCs[kt] = *(const s16x8*)(pk_gC + ((size_t)(kt * 14 + 7 + w) * 64 + l) * 8);
    }
    const int c = w * 16 + li;
    const bool cv = (c < 100);
    const float bg2_c = cv ? bg2[c] : 0.f;
    const float bh2_c = cv ? bh2[c] : 0.f;
    const float bmg_c = cv ? bmg[c] : 0.f;
    const float bsg_c = cv ? bsg[c] : 0.f;
    float b1r[4];
    #pragma unroll
    for (int nt_l = 0; nt_l < 4; ++nt_l) {
      int n = (w * 4 + nt_l) * 16 + li;
      bool is1 = n < 208;
      int j = is1 ? n : n - 208;
      b1r[nt_l] = (n < 416 && j < 200) ? (is1 ? bg1[j] : bh1[j]) : 0.f;
    }
    float pfn[4];
    #pragma unroll
    for (int q = 0; q < 4; ++q)
      pfn[q] = cv ? noise_gen[((size_t)0 * 128 + b0 + g * 4 + q) * 100 + c] : 0.f;
    __syncthreads();

    const int nA = (w < 6) ? 4 : 2;   // 26 valid nt tiles in ph1
    for (int t = 0; t < 256; ++t) {
      s16x8 az[4];
      #pragma unroll
      for (int kt = 0; kt < 4; ++kt)
        az[kt] = *(const s16x8*)(zbF + kt * 512 + l * 8);
      { // ph1: t1 = relu(z Wg1^T + bg1) ; t2 = relu(z Wh1^T + bh1)
        f32x4 a1[4];
        #pragma unroll
        for (int i = 0; i < 4; ++i) a1[i] = (f32x4){0.f, 0.f, 0.f, 0.f};
        if (w < 6) {
          #pragma unroll
          for (int kt = 0; kt < 4; ++kt) {
            #pragma unroll
            for (int nt_l = 0; nt_l < 4; ++nt_l) a1[nt_l] = mfma16(az[kt], wA[nt_l][kt], a1[nt_l]);
          }
        } else {
          #pragma unroll
          for (int kt = 0; kt < 4; ++kt) {
            a1[0] = mfma16(az[kt], wA[0][kt], a1[0]);
            a1[1] = mfma16(az[kt], wA[1][kt], a1[1]);
          }
        }
        for (int nt_l = 0; nt_l < nA; ++nt_l) {
          int n = (w * 4 + nt_l) * 16 + li;
          bool is1 = n < 208;
          int j = is1 ? n : n - 208;
          u16* dst = is1 ? t1F : t2F;
          float v0 = fmaxf(a1[nt_l][0] + b1r[nt_l], 0.f);
          float v1 = fmaxf(a1[nt_l][1] + b1r[nt_l], 0.f);
          float v2 = fmaxf(a1[nt_l][2] + b1r[nt_l], 0.f);
          float v3 = fmaxf(a1[nt_l][3] + b1r[nt_l], 0.f);
          u32 p01 = cvt_pk(v0, v1), p23 = cvt_pk(v2, v3);
          dst[fa(j, 4 * g + 0)] = (u16)p01;
          dst[fa(j, 4 * g + 1)] = (u16)(p01 >> 16);
          dst[fa(j, 4 * g + 2)] = (u16)p23;
          dst[fa(j, 4 * g + 3)] = (u16)(p23 >> 16);
        }
      }
      bar_lds();
      float muq[4];
      { // ph2: g, h_prop, m0; mu in-register; rh -> frags
        f32x4 ag = (f32x4){0.f,0.f,0.f,0.f}, ah = ag, am = ag;
        #pragma unroll
        for (int kt = 0; kt < 7; ++kt) {
          s16x8 x1 = *(const s16x8*)(t1F + kt * 512 + l * 8);
          ag = mfma16(x1, wBg[kt], ag);
        }
        #pragma unroll
        for (int kt = 0; kt < 7; ++kt) {
          s16x8 x2 = *(const s16x8*)(t2F + kt * 512 + l * 8);
          ah = mfma16(x2, wBh[kt], ah);
        }
        #pragma unroll
        for (int kt = 0; kt < 4; ++kt) am = mfma16(az[kt], wCm[kt], am);
        float rh[4];
        #pragma unroll
        for (int q = 0; q < 4; ++q) {
          float gv = sigmoid_f(ag[q] + bg2_c);
          float hp = ah[q] + bh2_c;
          float m0 = am[q] + bmg_c;
          muq[q] = hp * gv + m0 * (1.f - gv);
          rh[q] = fmaxf(hp, 0.f);
        }
        u32 p01 = cvt_pk(rh[0], rh[1]), p23 = cvt_pk(rh[2], rh[3]);
        rhbF[fa(c, 4 * g + 0)] = (u16)p01;
        rhbF[fa(c, 4 * g + 1)] = (u16)(p01 >> 16);
        rhbF[fa(c, 4 * g + 2)] = (u16)p23;
        rhbF[fa(c, 4 * g + 3)] = (u16)(p23 >> 16);
        if (cv) {
          #pragma unroll
          for (int q = 0; q < 4; ++q)
            mug[((size_t)(b0 + g * 4 + q) * 256 + t) * 100 + c] = muq[q];
        }
      }
      bar_lds();
      { // ph3: sigma = softplus(relu(h_prop) Wsg^T + bsg) ; z update
        f32x4 as2 = (f32x4){0.f,0.f,0.f,0.f};
        #pragma unroll
        for (int kt = 0; kt < 4; ++kt) {
          s16x8 xr = *(const s16x8*)(rhbF + kt * 512 + l * 8);
          as2 = mfma16(xr, wCs[kt], as2);
        }
        if (cv) {
          float sg[4], z[4];
          #pragma unroll
          for (int q = 0; q < 4; ++q) {
            sg[q] = softplus_f(as2[q] + bsg_c);
            z[q] = muq[q] + sqrtf(sg[q]) * pfn[q];
          }
          u32 p01 = cvt_pk(z[0], z[1]), p23 = cvt_pk(z[2], z[3]);
          u16 zb16[4] = { (u16)p01, (u16)(p01 >> 16), (u16)p23, (u16)(p23 >> 16) };
          #pragma unroll
          for (int q = 0; q < 4; ++q) {
            int r = g * 4 + q;
            sgg[((size_t)(b0 + r) * 256 + t) * 100 + c] = sg[q];
            zbF[fa(c, r)] = zb16[q];
          }
        }
        if (t < 255) {
          #pragma unroll
          for (int q = 0; q < 4; ++q)
            if (cv) pfn[q] = noise_gen[((size_t)(t + 1) * 128 + b0 + g * 4 + q) * 100 + c];
        }
      }
      bar_lds();
    }
  }
}

// ---------- K3: decoder, parallel over (B,S); z read from slot regions ----------
__global__ __launch_bounds__(448) void k_dec(
    const u16* __restrict__ slot,
    const u16* __restrict__ pk_e1, const u16* __restrict__ pk_e2, const u16* __restrict__ pk_e3,
    const float* __restrict__ be1, const float* __restrict__ be2, const float* __restrict__ be3,
    float* __restrict__ xh)
{
  __shared__ __align__(16) u16 sm[3 * 2176];
  u16* zb = sm; u16* e1b = sm + 2176; u16* e2b = sm + 4352;
  const int tid = threadIdx.x;
  const int w = tid >> 6, l = tid & 63, g = l >> 4, li = l & 15;
  const int cc = blockIdx.x;
  const int b = cc >> 4, s0 = (cc & 15) << 4;
  const int bid2 = b >> 4, r2 = b & 15;

  s16x8 w1[4], w2[4], w3[4];
  #pragma unroll
  for (int kt = 0; kt < 4; ++kt) {
    w1[kt] = *(const s16x8*)(pk_e1 + ((size_t)(kt * 7 + w) * 64 + l) * 8);
    w2[kt] = *(const s16x8*)(pk_e2 + ((size_t)(kt * 7 + w) * 64 + l) * 8);
    if (w < 6) w3[kt] = *(const s16x8*)(pk_e3 + ((size_t)(kt * 6 + w) * 64 + l) * 8);
  }
  {
    for (int idx = tid; idx < 224; idx += 448) {
      int r = idx / 14, cj = idx % 14;
      size_t src = ((size_t)((s0 + r) * 8 + bid2)) * 7168 + r2 * 112 + cj * 8;
      *(uint4*)(zb + r * 136 + cj * 8) = *(const uint4*)(slot + src);
    }
    for (int idx = tid; idx < 3 * 384; idx += 448) {   // zero the 24-col pads
      int bi = idx / 384, j = idx % 384;
      (sm + bi * 2176)[(j / 24) * 136 + 112 + (j % 24)] = 0;
    }
  }
  __syncthreads();
  const int c = w * 16 + li;
  { // e1 = relu(z We1^T + be1)
    f32x4 acc = (f32x4){0.f,0.f,0.f,0.f};
    #pragma unroll
    for (int kt = 0; kt < 4; ++kt) {
      s16x8 a = *(const s16x8*)(zb + li * 136 + kt * 32 + g * 8);
      acc = mfma16(a, w1[kt], acc);
    }
    float bias = (c < 100) ? be1[c] : 0.f;
    #pragma unroll
    for (int q = 0; q < 4; ++q)
      e1b[(g * 4 + q) * 136 + c] = f2bf(fmaxf(acc[q] + bias, 0.f));
  }
  bar_lds();
  { // e2 = relu(e1 We2^T + be2)
    f32x4 acc = (f32x4){0.f,0.f,0.f,0.f};
    #pragma unroll
    for (int kt = 0; kt < 4; ++kt) {
      s16x8 a = *(const s16x8*)(e1b + li * 136 + kt * 32 + g * 8);
      acc = mfma16(a, w2[kt], acc);
    }
    float bias = (c < 100) ? be2[c] : 0.f;
    #pragma unroll
    for (int q = 0; q < 4; ++q)
      e2b[(g * 4 + q) * 136 + c] = f2bf(fmaxf(acc[q] + bias, 0.f));
  }
  bar_lds();
  if (w < 6) { // x_hat = sigmoid(e2 We3^T + be3)
    f32x4 acc = (f32x4){0.f,0.f,0.f,0.f};
    #pragma unroll
    for (int kt = 0; kt < 4; ++kt) {
      s16x8 a = *(const s16x8*)(e2b + li * 136 + kt * 32 + g * 8);
      acc = mfma16(a, w3[kt], acc);
    }
    int n = w * 16 + li;
    if (n < 88) {
      float bias = be3[n];
      #pragma unroll
      for (int q = 0; q < 4; ++q)
        xh[((size_t)b * 256 + s0 + g * 4 + q) * 88 + n] = sigmoid_f(acc[q] + bias);
    }
  }
}

// ---------- host ----------
extern "C" void kernel_launch(void* const* d_in, const int* in_sizes, int n_in,
                              void* d_out, int out_size, void* d_ws, size_t ws_size,
                              hipStream_t stream) {
  const float* x      = (const float*)d_in[0];
  const float* Wih_b  = (const float*)d_in[5];
  const float* Whh_b  = (const float*)d_in[6];
  const float* bih_b  = (const float*)d_in[7];
  const float* bhh_b  = (const float*)d_in[8];
  const float* Wc     = (const float*)d_in[9];
  const float* bc     = (const float*)d_in[10];
  const float* Wmu    = (const float*)d_in[11];
  const float* bmu    = (const float*)d_in[12];
  const float* Wsig   = (const float*)d_in[13];
  const float* bsig   = (const float*)d_in[14];
  const float* We1    = (const float*)d_in[15];
  const float* be1    = (const float*)d_in[16];
  const float* We2    = (const float*)d_in[17];
  const float* be2    = (const float*)d_in[18];
  const float* We3    = (const float*)d_in[19];
  const float* be3    = (const float*)d_in[20];
  const float* Wg1    = (const float*)d_in[21];
  const float* bg1    = (const float*)d_in[22];
  const float* Wg2    = (const float*)d_in[23];
  const float* bg2    = (const float*)d_in[24];
  const float* Wh1    = (const float*)d_in[25];
  const float* bh1    = (const float*)d_in[26];
  const float* Wh2    = (const float*)d_in[27];
  const float* bh2    = (const float*)d_in[28];
  const float* Wmg    = (const float*)d_in[29];
  const float* bmg    = (const float*)d_in[30];
  const float* Wsg    = (const float*)d_in[31];
  const float* bsg    = (const float*)d_in[32];
  const float* noise_inf = (const float*)d_in[33];
  const float* z0_gen    = (const float*)d_in[34];
  const float* noise_gen = (const float*)d_in[35];

  u16* ws16 = (u16*)d_ws;
  float* out = (float*)d_out;
  float* xh  = out;                 // (B,S,88)
  float* mui = out + 2883584;       // (B,S,100)
  float* sgi = out + 6160384;
  float* mug = out + 9437184;
  float* sgg = out + 12713984;
  u16* slot = ws16 + U_SL;

  k_pack<<<1079, 64, 0, stream>>>(ws16, Whh_b, Wc, Wmu, Wsig, Wg1, Wh1, Wg2, Wh2,
                                  Wmg, Wsg, We1, We2, We3, Wih_b);
  k_proj<<<2048, 256, 0, stream>>>(x, bih_b, bhh_b, ws16 + U_IN, slot);
  k_scan<<<16, 448, 0, stream>>>(ws16 + U_RNN, ws16 + U_C1, ws16 + U_C2,
                                 ws16 + U_GA, ws16 + U_GB, ws16 + U_GC,
                                 slot,
                                 bc, bmu, bsig, noise_inf,
                                 z0_gen, bg1, bh1, bg2, bh2, bmg, bsg, noise_gen,
                                 mui, sgi, mug, sgg);
  k_dec<<<2048, 448, 0, stream>>>(slot, ws16 + U_E1, ws16 + U_E2, ws16 + U_E3,
                                  be1, be2, be3, xh);
}